// Round 7
// baseline (1385.014 us; speedup 1.0000x reference)
//
#include <hip/hip_runtime.h>
#include <math.h>

#define D 128
#define T 2048
#define BATCH 4
#define HMID 512
#define NLAYER 12
#define NBLK 256

#if defined(__has_builtin)
#if __has_builtin(__builtin_amdgcn_global_load_lds)
#define USE_GLL 1
#endif
#endif
#ifndef USE_GLL
#define USE_GLL 0
#endif

typedef unsigned short u16;
typedef __attribute__((ext_vector_type(8))) short bf16x8;
typedef __attribute__((ext_vector_type(16))) float f32x16;

__device__ inline u16 f2bf(float x) {
    unsigned u = __builtin_bit_cast(unsigned, x);
    return (u16)((u + 0x7FFFu + ((u >> 16) & 1u)) >> 16);
}
__device__ inline float bf2f(u16 v) {
    return __builtin_bit_cast(float, (unsigned)v << 16);
}
__device__ inline unsigned pkt(float a, float b) {
    return (__builtin_bit_cast(unsigned, a) >> 16) |
           (__builtin_bit_cast(unsigned, b) & 0xFFFF0000u);
}

// 154 KB shared-state for the persistent block (32 rows owned per block)
struct SM {
    float Hl[32][133];           // residual stream, f32, lives here all 12 layers
    u16 Qs[16][32][8];           // Q in MFMA B-fragment order [chunk][q][8]
    float mstat[4][2][32];       // per-wave m,l
    float Lbuf[32];              // 1/L per q
    float mu_s[32], rs_s[32];
    union {
        u16 KV[4][16384];        // attn: per-wave K(8192) + V^T(8192); O-partials overlay
        struct {
            u16 As[16][32][8];   // LN'd activations, A-frag order
            u16 midS[64][32][8]; // MLP hidden (bf16)
            u16 Wst[16][128][8]; // staged 128x128 weight tile
        } tl;
    } u;
};

// ---------------- one-shot grid barrier (256 co-resident blocks) ----------------
__device__ inline void grid_barrier(unsigned* slot) {
    __syncthreads();
    if (threadIdx.x == 0) {
        __threadfence();
        atomicAdd(slot, 1u);
        while (__hip_atomic_load(slot, __ATOMIC_ACQUIRE, __HIP_MEMORY_SCOPE_AGENT) < (unsigned)NBLK)
            __builtin_amdgcn_s_sleep(8);
        __threadfence();
    }
    __syncthreads();
}

// ---------------- row-local helpers ----------------
__device__ inline void ln_stats32(SM& sm, int tid) {
    const int q = tid >> 3, e8 = tid & 7;
    float s = 0.f;
#pragma unroll
    for (int c = 0; c < 16; c++) s += sm.Hl[q][e8 * 16 + c];
    s += __shfl_xor(s, 1); s += __shfl_xor(s, 2); s += __shfl_xor(s, 4);
    float mu = s * (1.f / D);
    float s2 = 0.f;
#pragma unroll
    for (int c = 0; c < 16; c++) {
        float d0 = sm.Hl[q][e8 * 16 + c] - mu;
        s2 += d0 * d0;
    }
    s2 += __shfl_xor(s2, 1); s2 += __shfl_xor(s2, 2); s2 += __shfl_xor(s2, 4);
    if (e8 == 0) { sm.mu_s[q] = mu; sm.rs_s[q] = rsqrtf(s2 * (1.f / D) + 1e-5f); }
}

__device__ inline void build_as(SM& sm, const float* __restrict__ g,
                                const float* __restrict__ bb, int tid) {
    const int row = tid >> 3, e8 = tid & 7;
    const float mu = sm.mu_s[row], rs = sm.rs_s[row];
#pragma unroll
    for (int cc = 0; cc < 2; cc++) {
        int c = e8 * 2 + cc;
        u16 tmp[8];
#pragma unroll
        for (int j = 0; j < 8; j++) {
            int d = c * 8 + j;
            tmp[j] = f2bf((sm.Hl[row][d] - mu) * rs * g[d] + bb[d]);
        }
        *(uint4*)&sm.u.tl.As[c][row ^ (c & 7)][0] = *(uint4*)tmp;
    }
}

__device__ inline void stage_w(const u16* __restrict__ W, int ldw, SM& sm, int tid) {
#pragma unroll
    for (int i = 0; i < 8; i++) {
        int ci = tid + 256 * i;
        int row = ci >> 4, c = ci & 15;
        *(uint4*)&sm.u.tl.Wst[c][row ^ c][0] = *(const uint4*)(W + (size_t)row * ldw + c * 8);
    }
}

__device__ inline f32x16 mm_32x128(SM& sm, int wv, int ql, int h) {
    f32x16 a;
#pragma unroll
    for (int r = 0; r < 16; r++) a[r] = 0.f;
#pragma unroll
    for (int s = 0; s < 8; s++) {
        int ch = 2 * s + h;
        bf16x8 af = *(const bf16x8*)&sm.u.tl.As[ch][ql ^ (ch & 7)][0];
        bf16x8 bf = *(const bf16x8*)&sm.u.tl.Wst[ch][(wv * 32 + ql) ^ ch][0];
        a = __builtin_amdgcn_mfma_f32_32x32x16_bf16(af, bf, a, 0, 0, 0);
    }
    return a;
}

// QKV for this block's rows (As holds LN'd rows). Q -> Qs (frag order, via
// swapped-operand MFMA giving lane=token); K,V -> global (double-buffered set).
__device__ inline void qkv_phase(SM& sm, const u16* __restrict__ Wqkvl,
                                 u16* __restrict__ kbn, u16* __restrict__ vtn,
                                 int m0, int bq, int tid) {
    const int wv = tid >> 6, l = tid & 63, h = l >> 5, ql = l & 31;
    const int tl0 = m0 & (T - 1);
    // --- Q (transposed output: lane = token) ---
    __syncthreads();
    stage_w(Wqkvl, D, sm, tid);
    __syncthreads();
    {
        f32x16 aq;
#pragma unroll
        for (int r = 0; r < 16; r++) aq[r] = 0.f;
#pragma unroll
        for (int s = 0; s < 8; s++) {
            int ch = 2 * s + h;
            bf16x8 af = *(const bf16x8*)&sm.u.tl.As[ch][ql ^ (ch & 7)][0];
            bf16x8 bf = *(const bf16x8*)&sm.u.tl.Wst[ch][(wv * 32 + ql) ^ ch][0];
            aq = __builtin_amdgcn_mfma_f32_32x32x16_bf16(bf, af, aq, 0, 0, 0);
        }
#pragma unroll
        for (int g = 0; g < 4; g++) {
            ushort4 o;
            o.x = f2bf(aq[4 * g + 0]); o.y = f2bf(aq[4 * g + 1]);
            o.z = f2bf(aq[4 * g + 2]); o.w = f2bf(aq[4 * g + 3]);
            *(ushort4*)&sm.Qs[4 * wv + g][ql][4 * h] = o;
        }
    }
    // --- K (row-major global) ---
    __syncthreads();
    stage_w(Wqkvl + 128 * D, D, sm, tid);
    __syncthreads();
    {
        f32x16 a = mm_32x128(sm, wv, ql, h);
        const int n = wv * 32 + ql;
#pragma unroll
        for (int r = 0; r < 16; r++) {
            int row = (r & 3) + 8 * (r >> 2) + 4 * h;
            kbn[(size_t)(m0 + row) * D + n] = f2bf(a[r]);
        }
    }
    // --- V (transposed per batch) ---
    __syncthreads();
    stage_w(Wqkvl + 2 * 128 * D, D, sm, tid);
    __syncthreads();
    {
        f32x16 a = mm_32x128(sm, wv, ql, h);
        const int n = wv * 32 + ql;
        u16* dst = vtn + (size_t)bq * D * T + (size_t)n * T + tl0;
#pragma unroll
        for (int g = 0; g < 4; g++) {
            ushort4 o;
            o.x = f2bf(a[4 * g + 0]); o.y = f2bf(a[4 * g + 1]);
            o.z = f2bf(a[4 * g + 2]); o.w = f2bf(a[4 * g + 3]);
            *(ushort4*)(dst + 8 * g + 4 * h) = o;
        }
    }
}

// Attention: 32 q rows (block-local Qs), 4 waves split 2048 keys (512 each),
// per-wave private LDS staging -> no block barrier in the key loop.
__device__ inline void attn_phase(SM& sm, const u16* __restrict__ kbl,
                                  const u16* __restrict__ vtl, int tid) {
    const int w = tid >> 6, l = tid & 63, h = l >> 5, ql = l & 31;
    u16* Kw = &sm.u.KV[w][0];
    u16* Vw = &sm.u.KV[w][8192];
    bf16x8 qf[8];
#pragma unroll
    for (int c = 0; c < 8; c++) qf[c] = *(const bf16x8*)&sm.Qs[2 * c + h][ql][0];
    f32x16 ot[4];
#pragma unroll
    for (int t = 0; t < 4; t++)
#pragma unroll
        for (int r = 0; r < 16; r++) ot[t][r] = 0.f;
    float m_run = -1e30f, l_run = 0.f;

    for (int kt = 0; kt < 8; kt++) {
        const int k0 = w * 512 + kt * 64;
#if USE_GLL
        __builtin_amdgcn_s_waitcnt(0xC07F);  // lgkmcnt(0): prior ds_reads drained
#pragma unroll
        for (int i = 0; i < 16; i++) {
            int s = i * 64 + l;
            int row = s >> 4, ch = (s & 15) ^ (row & 7);
            __builtin_amdgcn_global_load_lds(
                (const __attribute__((address_space(1))) void*)(kbl + (size_t)(k0 + row) * D + ch * 8),
                (__attribute__((address_space(3))) void*)(Kw + i * 512), 16, 0, 0);
        }
#pragma unroll
        for (int i = 0; i < 16; i++) {
            int s = i * 64 + l;
            int dd = s >> 3, ch = (s & 7) ^ (dd & 7);
            __builtin_amdgcn_global_load_lds(
                (const __attribute__((address_space(1))) void*)(vtl + (size_t)dd * T + k0 + ch * 8),
                (__attribute__((address_space(3))) void*)(Vw + i * 512), 16, 0, 0);
        }
        __builtin_amdgcn_s_waitcnt(0x0F70);  // vmcnt(0): this wave's tiles landed
#else
#pragma unroll
        for (int i = 0; i < 16; i++) {
            int s = i * 64 + l;
            int row = s >> 4, ch = (s & 15) ^ (row & 7);
            *(uint4*)(Kw + (size_t)s * 8) = *(const uint4*)(kbl + (size_t)(k0 + row) * D + ch * 8);
            int dd = s >> 3, ch2 = (s & 7) ^ (dd & 7);
            *(uint4*)(Vw + (size_t)s * 8) = *(const uint4*)(vtl + (size_t)dd * T + k0 + ch2 * 8);
        }
#endif
        // S^T = K * Q^T
        f32x16 st0, st1;
#pragma unroll
        for (int r = 0; r < 16; r++) { st0[r] = 0.f; st1[r] = 0.f; }
#pragma unroll
        for (int c = 0; c < 8; c++) {
            int ch = c * 2 + h;
            bf16x8 k0f = *(const bf16x8*)&Kw[((size_t)ql * 16 + (ch ^ (ql & 7))) * 8];
            bf16x8 k1f = *(const bf16x8*)&Kw[((size_t)(32 + ql) * 16 + (ch ^ (ql & 7))) * 8];
            st0 = __builtin_amdgcn_mfma_f32_32x32x16_bf16(k0f, qf[c], st0, 0, 0, 0);
            st1 = __builtin_amdgcn_mfma_f32_32x32x16_bf16(k1f, qf[c], st1, 0, 0, 0);
        }
        // online softmax (exp2 domain)
        float mx = m_run;
#pragma unroll
        for (int r = 0; r < 16; r++) mx = fmaxf(mx, fmaxf(st0[r], st1[r]));
        mx = fmaxf(mx, __shfl_xor(mx, 32));
        float alpha = exp2f(m_run - mx);
        m_run = mx;
        float rs = 0.f;
#pragma unroll
        for (int r = 0; r < 16; r++) {
            float p0 = exp2f(st0[r] - mx); st0[r] = p0;
            float p1 = exp2f(st1[r] - mx); st1[r] = p1;
            rs += p0 + p1;
        }
        rs += __shfl_xor(rs, 32);
        l_run = l_run * alpha + rs;
        uint2 pk0[4], pk1[4];
#pragma unroll
        for (int g = 0; g < 4; g++) {
            pk0[g].x = pkt(st0[4 * g + 0], st0[4 * g + 1]);
            pk0[g].y = pkt(st0[4 * g + 2], st0[4 * g + 3]);
            pk1[g].x = pkt(st1[4 * g + 0], st1[4 * g + 1]);
            pk1[g].y = pkt(st1[4 * g + 2], st1[4 * g + 3]);
        }
#pragma unroll
        for (int t = 0; t < 4; t++)
#pragma unroll
            for (int r = 0; r < 16; r++) ot[t][r] *= alpha;
#pragma unroll
        for (int c = 0; c < 4; c++) {
            const uint2* pk = (c < 2) ? pk0 : pk1;
            const int cc = c & 1;
            uint2 own = h ? pk[2 * cc + 1] : pk[2 * cc];
            uint2 snd = h ? pk[2 * cc] : pk[2 * cc + 1];
            uint2 rcv;
            rcv.x = (unsigned)__shfl_xor((int)snd.x, 32);
            rcv.y = (unsigned)__shfl_xor((int)snd.y, 32);
            uint4 fr;
            fr.x = h ? rcv.x : own.x;
            fr.y = h ? rcv.y : own.y;
            fr.z = h ? own.x : rcv.x;
            fr.w = h ? own.y : rcv.y;
            bf16x8 pf = __builtin_bit_cast(bf16x8, fr);
            int ch = c * 2 + h;
#pragma unroll
            for (int t = 0; t < 4; t++) {
                bf16x8 vf = *(const bf16x8*)&Vw[(((size_t)(t * 32 + ql)) * 8 + (ch ^ (ql & 7))) * 8];
                ot[t] = __builtin_amdgcn_mfma_f32_32x32x16_bf16(vf, pf, ot[t], 0, 0, 0);
            }
        }
    }
    // cross-wave merge (exp2 domain), O pre-scaled, then reduce into Hl (+residual)
    if (h == 0) { sm.mstat[w][0][ql] = m_run; sm.mstat[w][1][ql] = l_run; }
    __syncthreads();
    float M = fmaxf(fmaxf(sm.mstat[0][0][ql], sm.mstat[1][0][ql]),
                    fmaxf(sm.mstat[2][0][ql], sm.mstat[3][0][ql]));
    float L = 0.f;
#pragma unroll
    for (int ww = 0; ww < 4; ww++) L += sm.mstat[ww][1][ql] * exp2f(sm.mstat[ww][0][ql] - M);
    float fown = exp2f(m_run - M);
    float* Ow = (float*)&sm.u.KV[w][0];
#pragma unroll
    for (int t = 0; t < 4; t++)
#pragma unroll
        for (int r = 0; r < 16; r++) {
            int dd = (r & 3) + 8 * (r >> 2) + 4 * h + 32 * t;
            Ow[dd * 32 + ql] = ot[t][r] * fown;
        }
    if (w == 0 && h == 0) sm.Lbuf[ql] = 1.f / L;
    __syncthreads();
    const int q2 = tid & 31, dg8 = tid >> 5;
    float invL = sm.Lbuf[q2];
#pragma unroll
    for (int i = 0; i < 16; i++) {
        int d = dg8 * 16 + i;
        float s = 0.f;
#pragma unroll
        for (int ww = 0; ww < 4; ww++) s += ((const float*)&sm.u.KV[ww][0])[d * 32 + q2];
        sm.Hl[q2][d] += s * invL;
    }
    __syncthreads();
}

// LN2 + MLP1(gelu) + MLP2 + residual (all on Hl)
__device__ inline void tail_phase(SM& sm, const float* __restrict__ g2,
                                  const float* __restrict__ b2l,
                                  const u16* __restrict__ W1l, const float* __restrict__ b1l,
                                  const u16* __restrict__ W2l, const float* __restrict__ b2bias,
                                  int tid) {
    const int wv = tid >> 6, l = tid & 63, h = l >> 5, ql = l & 31;
    ln_stats32(sm, tid);
    __syncthreads();
    build_as(sm, g2, b2l, tid);
#pragma unroll
    for (int nc = 0; nc < 4; nc++) {
        __syncthreads();
        stage_w(W1l + (size_t)nc * 128 * D, D, sm, tid);
        __syncthreads();
        f32x16 a = mm_32x128(sm, wv, ql, h);
        const int n = nc * 128 + wv * 32 + ql;
        const int ch2 = n >> 3, sub = n & 7;
        const float bv = b1l[n];
#pragma unroll
        for (int r = 0; r < 16; r++) {
            int row = (r & 3) + 8 * (r >> 2) + 4 * h;
            float v = a[r] + bv;
            v = 0.5f * v * (1.f + erff(v * 0.7071067811865475f));
            sm.u.tl.midS[ch2][row ^ (ch2 & 7)][sub] = f2bf(v);
        }
    }
    f32x16 a2;
#pragma unroll
    for (int r = 0; r < 16; r++) a2[r] = 0.f;
#pragma unroll
    for (int kc = 0; kc < 4; kc++) {
        __syncthreads();
        stage_w(W2l + (size_t)kc * 128, HMID, sm, tid);
        __syncthreads();
#pragma unroll
        for (int s = 0; s < 8; s++) {
            int ch = 2 * s + h;
            int gch = kc * 16 + ch;
            bf16x8 af = *(const bf16x8*)&sm.u.tl.midS[gch][ql ^ (gch & 7)][0];
            bf16x8 bf = *(const bf16x8*)&sm.u.tl.Wst[ch][(wv * 32 + ql) ^ ch][0];
            a2 = __builtin_amdgcn_mfma_f32_32x32x16_bf16(af, bf, a2, 0, 0, 0);
        }
    }
    {
        const int col = wv * 32 + ql;
        const float bv = b2bias[col];
#pragma unroll
        for (int r = 0; r < 16; r++) {
            int row = (r & 3) + 8 * (r >> 2) + 4 * h;
            sm.Hl[row][col] += a2[r] + bv;
        }
    }
    __syncthreads();
}

// ================= the megakernel =================
// grid = 256 blocks (1/CU, co-resident: 154 KB LDS forces 1 block/CU)
__global__ __launch_bounds__(256, 1) void megakernel(
    const int* __restrict__ x, const float* __restrict__ pos,
    const float* __restrict__ Wq, const float* __restrict__ Wk, const float* __restrict__ Wv,
    const float* __restrict__ ln1g, const float* __restrict__ ln1b,
    const float* __restrict__ W1, const float* __restrict__ b1,
    const float* __restrict__ W2, const float* __restrict__ b2,
    const float* __restrict__ ln2g, const float* __restrict__ ln2b,
    const float* __restrict__ Wro, const float* __restrict__ bro,
    float* __restrict__ out,
    u16* __restrict__ Wqkv, u16* __restrict__ W1b, u16* __restrict__ W2b,
    u16* __restrict__ kb0, u16* __restrict__ vt0,
    u16* __restrict__ kb1, u16* __restrict__ vt1,
    unsigned* __restrict__ bar) {
    __shared__ SM sm;
    const int tid = threadIdx.x;
    const int bid = blockIdx.x;
    const int m0 = bid * 32;
    const int bq = bid >> 6;
    int bslot = 0;
    const float QSCALE = 1.4426950408889634f / 11.313708498984761f;  // log2e/sqrt(D)

    // phase 0: weight conversion (grid-stride over all weights)
    {
        const int NQ = NLAYER * 3 * D * D, NW = NLAYER * HMID * D;
        for (int idx = bid * 256 + tid; idx < NQ + 2 * NW; idx += NBLK * 256) {
            if (idx < NQ) {
                int lN = idx / (3 * D * D);
                int rem = idx - lN * (3 * D * D);
                int s = rem >> 14, off = rem & 16383;
                const float* src = (s == 0) ? Wq : ((s == 1) ? Wk : Wv);
                Wqkv[idx] = f2bf(src[lN * 16384 + off] * ((s == 0) ? QSCALE : 1.f));
            } else if (idx < NQ + NW) {
                W1b[idx - NQ] = f2bf(W1[idx - NQ]);
            } else {
                W2b[idx - NQ - NW] = f2bf(W2[idx - NQ - NW]);
            }
        }
    }
    grid_barrier(&bar[bslot++]);

    // phase 1: embed -> Hl, LN1 -> As, QKV(layer 0)
    {
        const int d = tid & 127, rr = tid >> 7;
#pragma unroll
        for (int i = 0; i < 16; i++) {
            int row = rr * 16 + i;
            int tok = m0 + row;
            float e = 0.f;
            if (d < 64) {
                float df = (float)d - (float)x[tok];
                e = -0.5f * df * df;
            }
            sm.Hl[row][d] = e + pos[(size_t)(tok & (T - 1)) * D + d];
        }
    }
    __syncthreads();
    ln_stats32(sm, tid);
    __syncthreads();
    build_as(sm, ln1g, ln1b, tid);
    qkv_phase(sm, Wqkv, kb0, vt0, m0, bq, tid);
    grid_barrier(&bar[bslot++]);

    for (int lay = 0; lay < NLAYER; lay++) {
        const u16* kbr = (lay & 1) ? kb1 : kb0;
        const u16* vtr = (lay & 1) ? vt1 : vt0;
        attn_phase(sm, kbr + (size_t)bq * T * D, vtr + (size_t)bq * D * T, tid);
        tail_phase(sm, ln2g + (size_t)lay * D, ln2b + (size_t)lay * D,
                   W1b + (size_t)lay * HMID * D, b1 + (size_t)lay * HMID,
                   W2b + (size_t)lay * D * HMID, b2 + (size_t)lay * D, tid);
        if (lay < NLAYER - 1) {
            ln_stats32(sm, tid);
            __syncthreads();
            build_as(sm, ln1g + (size_t)(lay + 1) * D, ln1b + (size_t)(lay + 1) * D, tid);
            u16* kbn = ((lay + 1) & 1) ? kb1 : kb0;
            u16* vtn = ((lay + 1) & 1) ? vt1 : vt0;
            qkv_phase(sm, Wqkv + (size_t)(lay + 1) * 3 * D * D, kbn, vtn, m0, bq, tid);
            grid_barrier(&bar[bslot++]);
        } else {
            const int q = tid >> 3, e8 = tid & 7;
            float s = 0.f;
#pragma unroll
            for (int c = 0; c < 16; c++) s += sm.Hl[q][e8 * 16 + c] * Wro[e8 * 16 + c];
            s += __shfl_xor(s, 1); s += __shfl_xor(s, 2); s += __shfl_xor(s, 4);
            if (e8 == 0) out[m0 + q] = s + bro[0];
        }
    }
}

extern "C" void kernel_launch(void* const* d_in, const int* in_sizes, int n_in,
                              void* d_out, int out_size, void* d_ws, size_t ws_size,
                              hipStream_t stream) {
    const int* x = (const int*)d_in[0];
    const float* pos = (const float*)d_in[1];
    const float* Wq = (const float*)d_in[2];
    const float* Wk = (const float*)d_in[3];
    const float* Wv = (const float*)d_in[4];
    const float* ln1g = (const float*)d_in[5];
    const float* ln1b = (const float*)d_in[6];
    const float* W1 = (const float*)d_in[7];
    const float* b1 = (const float*)d_in[8];
    const float* W2 = (const float*)d_in[9];
    const float* b2 = (const float*)d_in[10];
    const float* ln2g = (const float*)d_in[11];
    const float* ln2b = (const float*)d_in[12];
    const float* Wro = (const float*)d_in[13];
    const float* bro = (const float*)d_in[14];
    float* out = (float*)d_out;

    u16* wsu = (u16*)d_ws;
    u16* kb0 = wsu;                          // [8192][128] bf16
    u16* vt0 = wsu + 1048576;                // [B][128][2048]
    u16* kb1 = wsu + 2097152;
    u16* vt1 = wsu + 3145728;
    u16* Wqkv = wsu + 4194304;               // 589824
    u16* W1b = Wqkv + (size_t)NLAYER * 3 * D * D;   // 786432
    u16* W2b = W1b + (size_t)NLAYER * HMID * D;     // 786432
    unsigned* bar = (unsigned*)((char*)d_ws + 14 * 1024 * 1024);

    hipMemsetAsync(bar, 0, 16 * sizeof(unsigned), stream);
    megakernel<<<dim3(NBLK), dim3(256), 0, stream>>>(
        x, pos, Wq, Wk, Wv, ln1g, ln1b, W1, b1, W2, b2, ln2g, ln2b, Wro, bro, out,
        Wqkv, W1b, W2b, kb0, vt0, kb1, vt1, bar);
}

// Round 8
// 607.946 us; speedup vs baseline: 2.2782x; 2.2782x over previous
//
#include <hip/hip_runtime.h>
#include <math.h>

#define D 128
#define T 2048
#define BATCH 4
#define HMID 512
#define NLAYER 12

#define KSPLIT 8
#define KPB (T / KSPLIT)   // 256 keys per attn block
#define BK 64

#if defined(__has_builtin)
#if __has_builtin(__builtin_amdgcn_global_load_lds)
#define USE_GLL 1
#endif
#endif
#ifndef USE_GLL
#define USE_GLL 0
#endif

typedef unsigned short u16;
typedef __attribute__((ext_vector_type(8))) short bf16x8;
typedef __attribute__((ext_vector_type(16))) float f32x16;

__device__ inline u16 f2bf(float x) {
    unsigned u = __builtin_bit_cast(unsigned, x);
    return (u16)((u + 0x7FFFu + ((u >> 16) & 1u)) >> 16);
}
__device__ inline float bf2f(u16 v) {
    return __builtin_bit_cast(float, (unsigned)v << 16);
}
// truncating pack of two f32 -> bf16x2
__device__ inline unsigned pkt(float a, float b) {
    return (__builtin_bit_cast(unsigned, a) >> 16) |
           (__builtin_bit_cast(unsigned, b) & 0xFFFF0000u);
}

// ================= shared device helpers (32-row blocks) =================
__device__ inline void ln_stats32(const float (*Ct)[133], float* mu_s, float* rs_s, int tid) {
    const int q = tid >> 3, e8 = tid & 7;
    float s = 0.f;
#pragma unroll
    for (int c = 0; c < 16; c++) s += Ct[q][e8 * 16 + c];
    s += __shfl_xor(s, 1); s += __shfl_xor(s, 2); s += __shfl_xor(s, 4);
    float mu = s * (1.f / D);
    float s2 = 0.f;
#pragma unroll
    for (int c = 0; c < 16; c++) {
        float d0 = Ct[q][e8 * 16 + c] - mu;
        s2 += d0 * d0;
    }
    s2 += __shfl_xor(s2, 1); s2 += __shfl_xor(s2, 2); s2 += __shfl_xor(s2, 4);
    if (e8 == 0) { mu_s[q] = mu; rs_s[q] = rsqrtf(s2 * (1.f / D) + 1e-5f); }
}

__device__ inline void build_as(const float (*Ct)[133], const float* mu_s, const float* rs_s,
                                const float* __restrict__ g, const float* __restrict__ bb,
                                u16* As, int tid) {
    const int row = tid >> 3, e8 = tid & 7;
    const float mu = mu_s[row], rs = rs_s[row];
#pragma unroll
    for (int cc = 0; cc < 2; cc++) {
        int c = e8 * 2 + cc;
        u16 tmp[8];
#pragma unroll
        for (int j = 0; j < 8; j++) {
            int d = c * 8 + j;
            tmp[j] = f2bf((Ct[row][d] - mu) * rs * g[d] + bb[d]);
        }
        *(uint4*)&As[((size_t)c * 32 + (row ^ (c & 7))) * 8] = *(uint4*)tmp;
    }
}

__device__ inline void stage_w(const u16* __restrict__ W, int ldw, u16* Wst, int tid) {
#pragma unroll
    for (int i = 0; i < 8; i++) {
        int ci = tid + 256 * i;
        int row = ci >> 4, c = ci & 15;
        *(uint4*)&Wst[((size_t)c * 128 + (row ^ c)) * 8] =
            *(const uint4*)(W + (size_t)row * ldw + c * 8);
    }
}

__device__ inline f32x16 mm_32x128(const u16* As, const u16* Wst, int wv, int ql, int h) {
    f32x16 a;
#pragma unroll
    for (int r = 0; r < 16; r++) a[r] = 0.f;
#pragma unroll
    for (int s = 0; s < 8; s++) {
        int ch = 2 * s + h;
        bf16x8 af = *(const bf16x8*)&As[((size_t)ch * 32 + (ql ^ (ch & 7))) * 8];
        bf16x8 bf = *(const bf16x8*)&Wst[((size_t)ch * 128 + ((wv * 32 + ql) ^ ch)) * 8];
        a = __builtin_amdgcn_mfma_f32_32x32x16_bf16(af, bf, a, 0, 0, 0);
    }
    return a;
}

__device__ inline void qkv_phase(const u16* As, const u16* __restrict__ Wqkvl, u16* Wst,
                                 u16* __restrict__ qb, u16* __restrict__ kb,
                                 u16* __restrict__ vt, int m0, int tid) {
    const int wv = tid >> 6, l = tid & 63, h = l >> 5, ql = l & 31;
    const int bbk = m0 >> 11;
    const int tl0 = m0 & 2047;
#pragma unroll
    for (int sl = 0; sl < 3; sl++) {
        __syncthreads();
        stage_w(Wqkvl + (size_t)sl * 128 * D, D, Wst, tid);
        __syncthreads();
        f32x16 a = mm_32x128(As, Wst, wv, ql, h);
        const int n = wv * 32 + ql;
        if (sl == 2) {
            u16* dst = vt + (size_t)bbk * D * T + (size_t)n * T + tl0;
#pragma unroll
            for (int g = 0; g < 4; g++) {
                ushort4 o;
                o.x = f2bf(a[4 * g + 0]);
                o.y = f2bf(a[4 * g + 1]);
                o.z = f2bf(a[4 * g + 2]);
                o.w = f2bf(a[4 * g + 3]);
                *(ushort4*)(dst + 8 * g + 4 * h) = o;
            }
        } else {
            u16* dst = (sl == 0) ? qb : kb;
#pragma unroll
            for (int r = 0; r < 16; r++) {
                int row = (r & 3) + 8 * (r >> 2) + 4 * h;
                dst[(size_t)(m0 + row) * D + n] = f2bf(a[r]);
            }
        }
    }
}

// ================= weight conversion =================
__global__ __launch_bounds__(256) void conv_all(const float* __restrict__ Wq,
                                                const float* __restrict__ Wk,
                                                const float* __restrict__ Wv,
                                                const float* __restrict__ W1,
                                                const float* __restrict__ W2,
                                                u16* __restrict__ Wqkv,
                                                u16* __restrict__ W1b,
                                                u16* __restrict__ W2b, float qscale) {
    const int NQ = NLAYER * 3 * D * D;
    const int NW = NLAYER * HMID * D;
    int idx = blockIdx.x * 256 + threadIdx.x;
    if (idx < NQ) {
        int lN = idx / (3 * D * D);
        int rem = idx - lN * (3 * D * D);
        int s = rem >> 14;
        int off = rem & 16383;
        const float* src = (s == 0) ? Wq : ((s == 1) ? Wk : Wv);
        Wqkv[idx] = f2bf(src[lN * 16384 + off] * ((s == 0) ? qscale : 1.f));
    } else if (idx < NQ + NW) {
        W1b[idx - NQ] = f2bf(W1[idx - NQ]);
    } else if (idx < NQ + 2 * NW) {
        W2b[idx - NQ - NW] = f2bf(W2[idx - NQ - NW]);
    }
}

// ================= embed + LN1 + QKV (layer 0 prologue) =================
__global__ __launch_bounds__(256, 1) void embed_qkv(const int* __restrict__ x,
                                                    const float* __restrict__ pos,
                                                    const float* __restrict__ g1,
                                                    const float* __restrict__ b1g,
                                                    const u16* __restrict__ Wqkv0,
                                                    u16* __restrict__ qb, u16* __restrict__ kb,
                                                    u16* __restrict__ vt,
                                                    float* __restrict__ H) {
    __shared__ float Ct[32][133];
    __shared__ float mu_s[32], rs_s[32];
    __shared__ u16 As[16 * 32 * 8];
    __shared__ u16 Wst[16 * 128 * 8];
    const int tid = threadIdx.x;
    const int m0 = blockIdx.x * 32;
    {
        const int d = tid & 127, rr = tid >> 7;
#pragma unroll
        for (int i = 0; i < 16; i++) {
            int row = rr * 16 + i;
            int tok = m0 + row;
            int t = tok & (T - 1);
            float e = 0.f;
            if (d < 64) {
                float diff = (float)d - (float)x[tok];
                e = -0.5f * diff * diff;
            }
            float v = e + pos[(size_t)t * D + d];
            Ct[row][d] = v;
            H[(size_t)tok * D + d] = v;
        }
    }
    __syncthreads();
    ln_stats32(Ct, mu_s, rs_s, tid);
    __syncthreads();
    build_as(Ct, mu_s, rs_s, g1, b1g, As, tid);
    qkv_phase(As, Wqkv0, Wst, qb, kb, vt, m0, tid);
}

// ================= MFMA flash attention: fixed-reference softmax =================
// Split-K merge renormalizes exactly from (m,l); within a block we use M0=0
// (scores are O(1) through 12 LN layers; exp2 safe to |s|<127). This removes
// the running max, alpha, and per-tile O rescale -> ~half the key-loop VALU.
__global__ __launch_bounds__(256, 2) void attn_mfma(const u16* __restrict__ qg,
                                                    const u16* __restrict__ kg,
                                                    const u16* __restrict__ vtg,
                                                    u16* __restrict__ Op,
                                                    float* __restrict__ ml) {
    __shared__ u16 Ks[64 * 128];
    __shared__ u16 Vt[128 * 64];
    const int tid = threadIdx.x;
    const int w = tid >> 6;
    const int l = tid & 63;
    const int h = l >> 5;
    const int ql = l & 31;
    const int qblk = blockIdx.x;
    const int ks = blockIdx.y;
    const int b = qblk >> 4;

    const size_t qrow = (size_t)qblk * 128 + w * 32 + ql;
    bf16x8 qf[8];
#pragma unroll
    for (int c = 0; c < 8; c++)
        qf[c] = *(const bf16x8*)(qg + qrow * D + c * 16 + h * 8);

    f32x16 ot[4];
#pragma unroll
    for (int t = 0; t < 4; t++)
#pragma unroll
        for (int r = 0; r < 16; r++) ot[t][r] = 0.f;
    float l_run = 0.f;

    const size_t kgb = (size_t)b * T * D;
    const size_t vtb = (size_t)b * D * T;

    for (int kt = 0; kt < KPB / BK; kt++) {
        const int kbase = ks * KPB + kt * BK;
        __syncthreads();
#if USE_GLL
#pragma unroll
        for (int i = 0; i < 4; i++) {
            int s = w * 256 + i * 64 + l;
            int row = s >> 4, ch = (s & 15) ^ (row & 7);
            __builtin_amdgcn_global_load_lds(
                (const __attribute__((address_space(1))) void*)(kg + kgb + (size_t)(kbase + row) * D + ch * 8),
                (__attribute__((address_space(3))) void*)&Ks[(w * 256 + i * 64) * 8], 16, 0, 0);
        }
#pragma unroll
        for (int i = 0; i < 4; i++) {
            int s = w * 256 + i * 64 + l;
            int dd = s >> 3, ch = (s & 7) ^ (dd & 7);
            __builtin_amdgcn_global_load_lds(
                (const __attribute__((address_space(1))) void*)(vtg + vtb + (size_t)dd * T + kbase + ch * 8),
                (__attribute__((address_space(3))) void*)&Vt[(w * 256 + i * 64) * 8], 16, 0, 0);
        }
#else
#pragma unroll
        for (int i = 0; i < 4; i++) {
            int s = tid + i * 256;
            int row = s >> 4, ch = (s & 15) ^ (row & 7);
            *(uint4*)&Ks[(size_t)s * 8] = *(const uint4*)(kg + kgb + (size_t)(kbase + row) * D + ch * 8);
            int dd = s >> 3, ch2 = (s & 7) ^ (dd & 7);
            *(uint4*)&Vt[(size_t)s * 8] = *(const uint4*)(vtg + vtb + (size_t)dd * T + kbase + ch2 * 8);
        }
#endif
        __syncthreads();
        // S^T = K * Q^T
        f32x16 st0, st1;
#pragma unroll
        for (int r = 0; r < 16; r++) { st0[r] = 0.f; st1[r] = 0.f; }
#pragma unroll
        for (int c = 0; c < 8; c++) {
            int ch = c * 2 + h;
            bf16x8 k0 = *(const bf16x8*)&Ks[(ql * 16 + (ch ^ (ql & 7))) * 8];
            bf16x8 k1 = *(const bf16x8*)&Ks[((32 + ql) * 16 + (ch ^ (ql & 7))) * 8];
            st0 = __builtin_amdgcn_mfma_f32_32x32x16_bf16(k0, qf[c], st0, 0, 0, 0);
            st1 = __builtin_amdgcn_mfma_f32_32x32x16_bf16(k1, qf[c], st1, 0, 0, 0);
        }
        // fixed-reference softmax: p = exp2(s), accumulate l
        float rs = 0.f;
#pragma unroll
        for (int r = 0; r < 16; r++) {
            float p0 = exp2f(st0[r]); st0[r] = p0;
            float p1 = exp2f(st1[r]); st1[r] = p1;
            rs += p0 + p1;
        }
        rs += __shfl_xor(rs, 32);
        l_run += rs;
        uint2 pk0[4], pk1[4];
#pragma unroll
        for (int g = 0; g < 4; g++) {
            pk0[g].x = pkt(st0[4 * g + 0], st0[4 * g + 1]);
            pk0[g].y = pkt(st0[4 * g + 2], st0[4 * g + 3]);
            pk1[g].x = pkt(st1[4 * g + 0], st1[4 * g + 1]);
            pk1[g].y = pkt(st1[4 * g + 2], st1[4 * g + 3]);
        }
#pragma unroll
        for (int c = 0; c < 4; c++) {
            const uint2* pk = (c < 2) ? pk0 : pk1;
            const int cc = c & 1;
            uint2 own = h ? pk[2 * cc + 1] : pk[2 * cc];
            uint2 snd = h ? pk[2 * cc] : pk[2 * cc + 1];
            uint2 rcv;
            rcv.x = (unsigned)__shfl_xor((int)snd.x, 32);
            rcv.y = (unsigned)__shfl_xor((int)snd.y, 32);
            uint4 fr;
            fr.x = h ? rcv.x : own.x;
            fr.y = h ? rcv.y : own.y;
            fr.z = h ? own.x : rcv.x;
            fr.w = h ? own.y : rcv.y;
            bf16x8 pf = __builtin_bit_cast(bf16x8, fr);
            int ch = c * 2 + h;
#pragma unroll
            for (int t = 0; t < 4; t++) {
                bf16x8 vf = *(const bf16x8*)&Vt[((t * 32 + ql) * 8 + (ch ^ (ql & 7))) * 8];
                ot[t] = __builtin_amdgcn_mfma_f32_32x32x16_bf16(vf, pf, ot[t], 0, 0, 0);
            }
        }
    }
    size_t base = (((size_t)(qblk * KSPLIT + ks)) * 4 + w) * (128 * 32);
#pragma unroll
    for (int t = 0; t < 4; t++)
#pragma unroll
        for (int r = 0; r < 16; r++) {
            int dd = (r & 3) + 8 * (r >> 2) + 4 * h + 32 * t;
            Op[base + (size_t)dd * 32 + ql] = f2bf(ot[t][r]);
        }
    if (h == 0) {
        int qi = w * 32 + ql;
        ml[(size_t)(qblk * KSPLIT + ks) * 256 + qi] = 0.f;   // fixed reference M0=0
        ml[(size_t)(qblk * KSPLIT + ks) * 256 + 128 + qi] = l_run;
    }
}

// ====== layer tail: merge + resid + LN2 + MLP1 + MLP2 + resid + LN1' + QKV' ======
template <int LAST>
__global__ __launch_bounds__(256, 1) void layer_tail(
    const u16* __restrict__ Op, const float* __restrict__ ml,
    float* __restrict__ H,
    const float* __restrict__ g2, const float* __restrict__ b2l,
    const u16* __restrict__ W1l, const float* __restrict__ b1l,
    const u16* __restrict__ W2l, const float* __restrict__ b2bias,
    const float* __restrict__ g1n, const float* __restrict__ b1n,
    const u16* __restrict__ Wqkvn,
    u16* __restrict__ qb, u16* __restrict__ kb, u16* __restrict__ vt,
    const float* __restrict__ Wro, const float* __restrict__ bro,
    float* __restrict__ outp) {
    __shared__ float Ct[32][133];
    __shared__ float mu_s[32], rs_s[32];
    __shared__ u16 As[16 * 32 * 8];
    __shared__ u16 midS[64 * 32 * 8];
    __shared__ u16 Wst[16 * 128 * 8];

    const int tid = threadIdx.x;
    const int bid = blockIdx.x;
    const int qblk = bid >> 2;
    const int wq = bid & 3;
    const int m0 = bid * 32;
    const int wv = tid >> 6;
    const int l = tid & 63;
    const int h = l >> 5;
    const int ql = l & 31;

    // ---- merge split-K partials ----
    {
        const int dg = tid >> 5;
        float m[KSPLIT], lv[KSPLIT];
        float M = -1e30f;
#pragma unroll
        for (int ks = 0; ks < KSPLIT; ks++) {
            m[ks] = ml[(size_t)(qblk * KSPLIT + ks) * 256 + wq * 32 + ql];
            lv[ks] = ml[(size_t)(qblk * KSPLIT + ks) * 256 + 128 + wq * 32 + ql];
            M = fmaxf(M, m[ks]);
        }
        float L = 0.f, f[KSPLIT];
#pragma unroll
        for (int ks = 0; ks < KSPLIT; ks++) { f[ks] = exp2f(m[ks] - M); L += lv[ks] * f[ks]; }
        float invL = 1.f / L;
        float acc[16];
#pragma unroll
        for (int i = 0; i < 16; i++) acc[i] = 0.f;
#pragma unroll
        for (int ks = 0; ks < KSPLIT; ks++) {
            size_t base = (((size_t)(qblk * KSPLIT + ks)) * 4 + wq) * (128 * 32);
#pragma unroll
            for (int i = 0; i < 16; i++)
                acc[i] += bf2f(Op[base + (size_t)(dg * 16 + i) * 32 + ql]) * f[ks];
        }
#pragma unroll
        for (int i = 0; i < 16; i++) Ct[ql][dg * 16 + i] = acc[i] * invL;
    }
    __syncthreads();
    // ---- residual with pre-layer H ----
    {
        const int d = tid & 127, rr = tid >> 7;
#pragma unroll
        for (int i = 0; i < 16; i++) {
            int row = rr * 16 + i;
            Ct[row][d] += H[(size_t)(m0 + row) * D + d];
        }
    }
    __syncthreads();
    // ---- LN2 -> As ----
    ln_stats32(Ct, mu_s, rs_s, tid);
    __syncthreads();
    build_as(Ct, mu_s, rs_s, g2, b2l, As, tid);
    // ---- MLP1 (gelu) -> midS ----
#pragma unroll
    for (int nc = 0; nc < 4; nc++) {
        __syncthreads();
        stage_w(W1l + (size_t)nc * 128 * D, D, Wst, tid);
        __syncthreads();
        f32x16 a = mm_32x128(As, Wst, wv, ql, h);
        const int n = nc * 128 + wv * 32 + ql;
        const int ch2 = n >> 3, sub = n & 7;
        const float bv = b1l[n];
#pragma unroll
        for (int r = 0; r < 16; r++) {
            int row = (r & 3) + 8 * (r >> 2) + 4 * h;
            float v = a[r] + bv;
            v = 0.5f * v * (1.f + erff(v * 0.7071067811865475f));
            midS[((size_t)ch2 * 32 + (row ^ (ch2 & 7))) * 8 + sub] = f2bf(v);
        }
    }
    // ---- MLP2 ----
    f32x16 a2;
#pragma unroll
    for (int r = 0; r < 16; r++) a2[r] = 0.f;
#pragma unroll
    for (int kc = 0; kc < 4; kc++) {
        __syncthreads();
        stage_w(W2l + (size_t)kc * 128, HMID, Wst, tid);
        __syncthreads();
#pragma unroll
        for (int s = 0; s < 8; s++) {
            int ch = 2 * s + h;
            int gch = kc * 16 + ch;
            bf16x8 af = *(const bf16x8*)&midS[((size_t)gch * 32 + (ql ^ (gch & 7))) * 8];
            bf16x8 bf = *(const bf16x8*)&Wst[((size_t)ch * 128 + ((wv * 32 + ql) ^ ch)) * 8];
            a2 = __builtin_amdgcn_mfma_f32_32x32x16_bf16(af, bf, a2, 0, 0, 0);
        }
    }
    // ---- bias + residual -> Ct, write H ----
    {
        const int col = wv * 32 + ql;
        const float bv = b2bias[col];
#pragma unroll
        for (int r = 0; r < 16; r++) {
            int row = (r & 3) + 8 * (r >> 2) + 4 * h;
            float v = a2[r] + bv + Ct[row][col];
            Ct[row][col] = v;
            H[(size_t)(m0 + row) * D + col] = v;
        }
    }
    __syncthreads();
    if (LAST) {
        const int q = tid >> 3, e8 = tid & 7;
        float s = 0.f;
#pragma unroll
        for (int c = 0; c < 16; c++) s += Ct[q][e8 * 16 + c] * Wro[e8 * 16 + c];
        s += __shfl_xor(s, 1); s += __shfl_xor(s, 2); s += __shfl_xor(s, 4);
        if (e8 == 0) outp[m0 + q] = s + bro[0];
    } else {
        ln_stats32(Ct, mu_s, rs_s, tid);
        __syncthreads();
        build_as(Ct, mu_s, rs_s, g1n, b1n, As, tid);
        qkv_phase(As, Wqkvn, Wst, qb, kb, vt, m0, tid);
    }
}

extern "C" void kernel_launch(void* const* d_in, const int* in_sizes, int n_in,
                              void* d_out, int out_size, void* d_ws, size_t ws_size,
                              hipStream_t stream) {
    const int* x = (const int*)d_in[0];
    const float* pos = (const float*)d_in[1];
    const float* Wq = (const float*)d_in[2];
    const float* Wk = (const float*)d_in[3];
    const float* Wv = (const float*)d_in[4];
    const float* ln1g = (const float*)d_in[5];
    const float* ln1b = (const float*)d_in[6];
    const float* W1 = (const float*)d_in[7];
    const float* b1 = (const float*)d_in[8];
    const float* W2 = (const float*)d_in[9];
    const float* b2 = (const float*)d_in[10];
    const float* ln2g = (const float*)d_in[11];
    const float* ln2b = (const float*)d_in[12];
    const float* Wro = (const float*)d_in[13];
    const float* bro = (const float*)d_in[14];
    float* out = (float*)d_out;

    const size_t NTOK = (size_t)BATCH * T;  // 8192
    const size_t HSZ = NTOK * D;            // 1,048,576
    float* ws = (float*)d_ws;
    float* H = ws;                                   // f32 [8192][128]
    u16* qb = (u16*)(ws + HSZ);                      // bf16 [8192][128]
    u16* kb = (u16*)(ws + HSZ + HSZ / 2);
    u16* vt = (u16*)(ws + 2 * HSZ);                  // bf16 [B][128][2048]
    u16* Op = (u16*)(ws + 2 * HSZ + HSZ / 2);        // bf16 partials 16.8 MB
    float* mlbuf = ws + 7 * HSZ;                     // f32 131072
    u16* Wqkv = (u16*)(ws + 7 * HSZ + 131072);       // bf16 [L][3*128][128]
    u16* W1b = Wqkv + (size_t)NLAYER * 3 * D * D;
    u16* W2b = W1b + (size_t)NLAYER * HMID * D;

    const float qscale = 1.4426950408889634f / 11.313708498984761f;  // log2(e)/sqrt(D)

    conv_all<<<dim3(8448), 256, 0, stream>>>(Wq, Wk, Wv, W1, W2, Wqkv, W1b, W2b, qscale);
    embed_qkv<<<dim3(256), 256, 0, stream>>>(x, pos, ln1g, ln1b, Wqkv, qb, kb, vt, H);

    for (int lay = 0; lay < NLAYER; lay++) {
        attn_mfma<<<dim3(64, KSPLIT), 256, 0, stream>>>(qb, kb, vt, Op, mlbuf);
        if (lay < NLAYER - 1) {
            layer_tail<0><<<dim3(256), 256, 0, stream>>>(
                Op, mlbuf, H,
                ln2g + (size_t)lay * D, ln2b + (size_t)lay * D,
                W1b + (size_t)lay * HMID * D, b1 + (size_t)lay * HMID,
                W2b + (size_t)lay * D * HMID, b2 + (size_t)lay * D,
                ln1g + (size_t)(lay + 1) * D, ln1b + (size_t)(lay + 1) * D,
                Wqkv + (size_t)(lay + 1) * 3 * D * D,
                qb, kb, vt, Wro, bro, nullptr);
        } else {
            layer_tail<1><<<dim3(256), 256, 0, stream>>>(
                Op, mlbuf, H,
                ln2g + (size_t)lay * D, ln2b + (size_t)lay * D,
                W1b + (size_t)lay * HMID * D, b1 + (size_t)lay * HMID,
                W2b + (size_t)lay * D * HMID, b2 + (size_t)lay * D,
                ln1g, ln1b, Wqkv,
                qb, kb, vt, Wro, bro, out);
        }
    }
}